// Round 7
// baseline (128.910 us; speedup 1.0000x reference)
//
#include <hip/hip_runtime.h>
#include <math.h>

namespace {
constexpr int kN = 22;
constexpr int kF = 448;
constexpr int kNP = 484;
// kernel1 shared pool (floats): corr role needs 22*452 + 44 = 9988 (39.95 KB)
constexpr int kXStr = 452;                  // 16B-aligned rows, 452%32==4 bank spread
constexpr int kSm1 = kN * kXStr + 2 * kN;   // 9988
// GEMM overlays (union with corr pool): As[64][36]=2304 + Bs[64][68]=4352, red 2048
constexpr int kAStr = 36;
constexpr int kBStr = 68;
// kernel2
constexpr int kPStr = 68;
constexpr int kTStr = 66;                   // vbT row stride (even -> float2 aligned)

__device__ __forceinline__ void map_slot(int s, int& i, int& j) {
    // s<231: strict upper (i<j); else diagonal
    if (s < 231) {
        int rem = s, i0 = 0;
        while (rem >= 21 - i0) { rem -= 21 - i0; ++i0; }
        i = i0; j = i0 + 1 + rem;
    } else {
        i = j = s - 231;
    }
}
}

// =================== kernel 1: projections GEMM + corr ======================
// blocks [0, nGemm): 32x64 SGEMM tiles, 4x4 microtile, K-split-2 + LDS reduce
//   C = A(M,448) @ W(448,256); col tiles: 0:a1(+cb1) 1:a2 2:u1(+emb@sw1[0:64],+sb1)
//   3:u2(+emb@sw1[64:128])
// blocks [nGemm, nGemm+2B): per-(b,half) corr stats + |corr| rows
__global__ __launch_bounds__(256) void hgc_k1(
    const float* __restrict__ x,
    const float* __restrict__ cw1, const float* __restrict__ cb1,
    const float* __restrict__ emb,
    const float* __restrict__ sw1, const float* __restrict__ sb1,
    float* __restrict__ C, float* __restrict__ g,
    int M, int Mtiles, int nGemm)
{
    __shared__ __align__(16) float sm[kSm1];
    const int tid = threadIdx.x;

    if ((int)blockIdx.x < nGemm) {
        // ---------------- GEMM role ----------------
        float* As = sm;                 // As[k][m], [64][kAStr] (transposed)
        float* Bs = sm + 64 * kAStr;    // Bs[k][n], [64][kBStr]
        const int bm = blockIdx.x % Mtiles;
        const int bn = blockIdx.x / Mtiles;        // 0..3
        const int m0 = bm * 32;

        const float* Wsrc =
            (bn == 0) ? cw1 :
            (bn == 1) ? cw1 + 448 * 64 :
            (bn == 2) ? sw1 + 128 * 64 :
                        sw1 + 576 * 64;

        const int kg   = tid >> 7;      // K-half 0/1
        const int t128 = tid & 127;
        const int mg = t128 >> 4;       // rows mg*4 .. +3
        const int ng = t128 & 15;       // cols ng*4 .. +3
        float4 acc[4];
        #pragma unroll
        for (int i = 0; i < 4; ++i) acc[i] = float4{0, 0, 0, 0};

        float4 rA[2], rB[4];

        auto preMain = [&](int k0) {
            #pragma unroll
            for (int p = 0; p < 2; ++p) {
                const int idx = tid + p * 256;
                const int row = idx >> 4, kq = idx & 15;
                int m = m0 + row; if (m >= M) m = M - 1;
                rA[p] = *(const float4*)&x[(size_t)m * kF + k0 + kq * 4];
            }
            #pragma unroll
            for (int p = 0; p < 4; ++p) {
                const int idx = tid + p * 256;
                const int k = idx >> 4, nq = idx & 15;
                rB[p] = *(const float4*)&Wsrc[(size_t)(k0 + k) * 64 + nq * 4];
            }
        };
        auto preEmb = [&]() {
            const float* W2 = sw1 + (bn == 2 ? 0 : 64) * 64;
            #pragma unroll
            for (int p = 0; p < 2; ++p) {
                const int idx = tid + p * 256;
                const int row = idx >> 4, kq = idx & 15;
                const int r = (m0 + row) % kN;
                rA[p] = *(const float4*)&emb[(size_t)r * 64 + kq * 4];
            }
            #pragma unroll
            for (int p = 0; p < 4; ++p) {
                const int idx = tid + p * 256;
                const int k = idx >> 4, nq = idx & 15;
                rB[p] = *(const float4*)&W2[(size_t)k * 64 + nq * 4];
            }
        };
        auto commit = [&]() {
            #pragma unroll
            for (int p = 0; p < 2; ++p) {
                const int idx = tid + p * 256;
                const int row = idx >> 4, kq = idx & 15;
                As[(kq * 4 + 0) * kAStr + row] = rA[p].x;
                As[(kq * 4 + 1) * kAStr + row] = rA[p].y;
                As[(kq * 4 + 2) * kAStr + row] = rA[p].z;
                As[(kq * 4 + 3) * kAStr + row] = rA[p].w;
            }
            #pragma unroll
            for (int p = 0; p < 4; ++p) {
                const int idx = tid + p * 256;
                const int k = idx >> 4, nq = idx & 15;
                *(float4*)&Bs[k * kBStr + nq * 4] = rB[p];
            }
        };
        auto compute = [&]() {
            #pragma unroll 8
            for (int kk = 0; kk < 32; ++kk) {
                const int k = kg * 32 + kk;
                const float4 a4 = *(const float4*)&As[k * kAStr + mg * 4];
                const float4 b4 = *(const float4*)&Bs[k * kBStr + ng * 4];
                acc[0].x = fmaf(a4.x, b4.x, acc[0].x); acc[0].y = fmaf(a4.x, b4.y, acc[0].y);
                acc[0].z = fmaf(a4.x, b4.z, acc[0].z); acc[0].w = fmaf(a4.x, b4.w, acc[0].w);
                acc[1].x = fmaf(a4.y, b4.x, acc[1].x); acc[1].y = fmaf(a4.y, b4.y, acc[1].y);
                acc[1].z = fmaf(a4.y, b4.z, acc[1].z); acc[1].w = fmaf(a4.y, b4.w, acc[1].w);
                acc[2].x = fmaf(a4.z, b4.x, acc[2].x); acc[2].y = fmaf(a4.z, b4.y, acc[2].y);
                acc[2].z = fmaf(a4.z, b4.z, acc[2].z); acc[2].w = fmaf(a4.z, b4.w, acc[2].w);
                acc[3].x = fmaf(a4.w, b4.x, acc[3].x); acc[3].y = fmaf(a4.w, b4.y, acc[3].y);
                acc[3].z = fmaf(a4.w, b4.z, acc[3].z); acc[3].w = fmaf(a4.w, b4.w, acc[3].w);
            }
        };

        preMain(0);
        commit();
        __syncthreads();
        for (int c = 0; c < 7; ++c) {
            if (c < 6) preMain((c + 1) * 64);        // loads in flight during compute
            else if (bn >= 2) preEmb();
            compute();
            __syncthreads();
            if (c < 6 || bn >= 2) {
                commit();
                __syncthreads();
            }
        }
        if (bn >= 2) compute();                      // emb epilogue chunk

        // K-split reduction: kg=1 dumps accs into LDS (As region is dead), kg=0 adds
        __syncthreads();
        float* red = sm;                             // 2048 floats
        if (kg == 1) {
            #pragma unroll
            for (int i = 0; i < 4; ++i)
                *(float4*)&red[i * 512 + t128 * 4] = acc[i];
        }
        __syncthreads();
        if (kg == 0) {
            float4 bias = {0, 0, 0, 0};
            if (bn == 0)      bias = *(const float4*)&cb1[ng * 4];
            else if (bn == 2) bias = *(const float4*)&sb1[ng * 4];
            #pragma unroll
            for (int i = 0; i < 4; ++i) {
                const float4 r = *(const float4*)&red[i * 512 + t128 * 4];
                const int m = m0 + mg * 4 + i;
                if (m < M) {
                    float4 o;
                    o.x = acc[i].x + r.x + bias.x; o.y = acc[i].y + r.y + bias.y;
                    o.z = acc[i].z + r.z + bias.z; o.w = acc[i].w + r.w + bias.w;
                    *(float4*)&C[(size_t)m * 256 + bn * 64 + ng * 4] = o;
                }
            }
        }
    } else {
        // ---------------- corr role: 2 blocks/b, 11 rows each ----------------
        float* smu = sm + kN * kXStr;
        float* sis = smu + kN;
        const int cb = blockIdx.x - nGemm;
        const int b = cb >> 1;
        const int r0 = (cb & 1) * 11;

        const float4* xb4 = (const float4*)(x + (size_t)b * (kN * kF));
        for (int idx = tid; idx < kN * kF / 4; idx += 256) {
            const float4 v = xb4[idx];
            const int r = idx / 112;
            const int k = (idx - r * 112) * 4;
            float* d = sm + r * kXStr + k;
            d[0] = v.x; d[1] = v.y; d[2] = v.z; d[3] = v.w;
        }
        __syncthreads();

        {
            const int wid = tid >> 6, lane = tid & 63;
            for (int r = wid; r < kN; r += 4) {
                const float* row = sm + r * kXStr;
                float s = 0.f;
                #pragma unroll
                for (int c = 0; c < 7; ++c) s += row[c * 64 + lane];
                #pragma unroll
                for (int o = 32; o; o >>= 1) s += __shfl_xor(s, o, 64);
                const float mean = s * (1.f / 448.f);
                float ss = 0.f;
                #pragma unroll
                for (int c = 0; c < 7; ++c) { const float d = row[c * 64 + lane] - mean; ss = fmaf(d, d, ss); }
                #pragma unroll
                for (int o = 32; o; o >>= 1) ss += __shfl_xor(ss, o, 64);
                if (lane == 0) {
                    smu[r] = mean;
                    sis[r] = 1.f / (sqrtf(ss * (1.f / 447.f)) + 1e-8f);   // ddof=1
                }
            }
        }
        __syncthreads();

        for (int p = tid; p < 11 * kN; p += 256) {
            const int pi = p / 22;
            const int i = r0 + pi, j = p - pi * 22;
            const float4* ri = (const float4*)(sm + i * kXStr);
            const float4* rj = (const float4*)(sm + j * kXStr);
            float dot = 0.f;
            for (int q = 0; q < 112; ++q) {
                const float4 a = ri[q], bq = rj[q];
                dot = fmaf(a.x, bq.x, dot); dot = fmaf(a.y, bq.y, dot);
                dot = fmaf(a.z, bq.z, dot); dot = fmaf(a.w, bq.w, dot);
            }
            const float c = (dot - 448.f * smu[i] * smu[j]) * sis[i] * sis[j] * (1.f / 448.f);
            g[(size_t)b * kNP + i * 22 + j] = fabsf(c);
        }
    }
}

// ===== kernel 2: 4 blocks/b, 64 unique slots, single-pass (vbT k-major) =====
__global__ __launch_bounds__(256) void hgc_k2(
    const float* __restrict__ C, const float* __restrict__ g,
    const float* __restrict__ cw2, const float* __restrict__ cb2,
    const float* __restrict__ sw2, const float* __restrict__ sb2,
    const float* __restrict__ sw3, const float* __restrict__ sb3,
    const float* __restrict__ ln_g, const float* __restrict__ ln_b,
    const float* __restrict__ thr, const float* __restrict__ alpha_p,
    float* __restrict__ out)
{
    __shared__ __align__(16) float sp[4 * kN * kPStr];   // a1|a2|u1|u2
    __shared__ float sg[kNP];
    __shared__ __align__(16) float sw2s[2048];            // [k][o] 64x32
    __shared__ float scw2[64], slng[64], slnb[64], ssw3[32], ssb2[32];
    __shared__ float szc[128];                            // per-slot zc1,zc2
    __shared__ __align__(16) float vbT[64 * kTStr];       // [k][slot] post-LN V

    const int tid = threadIdx.x;
    const int b   = blockIdx.x >> 2;
    const int pb  = blockIdx.x & 3;

    #pragma unroll
    for (int a = 0; a < 4; ++a) {
        float* dst = sp + a * kN * kPStr;
        for (int idx = tid; idx < 352; idx += 256) {
            const int r = idx >> 4, kq = idx & 15;
            const float4 v = *(const float4*)&C[((size_t)(b * 22 + r)) * 256 + a * 64 + kq * 4];
            *(float4*)&dst[r * kPStr + kq * 4] = v;
        }
    }
    for (int idx = tid; idx < kNP; idx += 256) sg[idx] = g[(size_t)b * kNP + idx];
    {
        const float4* s4 = (const float4*)sw2;
        for (int idx = tid; idx < 512; idx += 256)
            *((float4*)(sw2s + idx * 4)) = s4[idx];
    }
    if (tid < 64)       { scw2[tid] = cw2[tid]; slng[tid] = ln_g[tid]; slnb[tid] = ln_b[tid]; }
    else if (tid < 96)  { ssw3[tid - 64] = sw3[tid - 64]; }
    else if (tid < 128) { ssb2[tid - 96] = sb2[tid - 96]; }
    __syncthreads();

    const float* sa1 = sp;
    const float* sa2 = sp + kN * kPStr;
    const float* su1 = sp + 2 * kN * kPStr;
    const float* su2 = sp + 3 * kN * kPStr;

    // ---- phase A: per-slot dual corr-dots + LN, 4 lanes/slot, 64 slots ----
    {
        const int sl = tid >> 2, t4 = tid & 3;
        const int s_ = pb * 64 + sl;
        const int s = (s_ < 253) ? s_ : 252;
        int i, j; map_slot(s, i, j);

        // dual corr-weight partial dots over k-slice t4*16..+15
        float zc1 = 0.f, zc2 = 0.f;
        {
            const float* a1i = sa1 + i * kPStr + t4 * 16;
            const float* a2j = sa2 + j * kPStr + t4 * 16;
            const float* a1j = sa1 + j * kPStr + t4 * 16;
            const float* a2i = sa2 + i * kPStr + t4 * 16;
            #pragma unroll
            for (int c4 = 0; c4 < 4; ++c4) {
                const float4 p = *(const float4*)(a1i + c4 * 4);
                const float4 q = *(const float4*)(a2j + c4 * 4);
                const float4 r = *(const float4*)(a1j + c4 * 4);
                const float4 t = *(const float4*)(a2i + c4 * 4);
                const float4 w = *(const float4*)(scw2 + t4 * 16 + c4 * 4);
                zc1 = fmaf(fmaxf(p.x + q.x, 0.f), w.x, zc1);
                zc1 = fmaf(fmaxf(p.y + q.y, 0.f), w.y, zc1);
                zc1 = fmaf(fmaxf(p.z + q.z, 0.f), w.z, zc1);
                zc1 = fmaf(fmaxf(p.w + q.w, 0.f), w.w, zc1);
                zc2 = fmaf(fmaxf(r.x + t.x, 0.f), w.x, zc2);
                zc2 = fmaf(fmaxf(r.y + t.y, 0.f), w.y, zc2);
                zc2 = fmaf(fmaxf(r.z + t.z, 0.f), w.z, zc2);
                zc2 = fmaf(fmaxf(r.w + t.w, 0.f), w.w, zc2);
            }
            zc1 += __shfl_xor(zc1, 1, 64); zc1 += __shfl_xor(zc1, 2, 64);
            zc2 += __shfl_xor(zc2, 1, 64); zc2 += __shfl_xor(zc2, 2, 64);
            if (t4 == 0) { szc[sl * 2] = zc1; szc[sl * 2 + 1] = zc2; }
        }

        // LN over h = u1[i] + u2[j] (i<=j), slice t4*16..+15
        float raw[16];
        float s1 = 0.f;
        {
            const float* pu1 = su1 + i * kPStr + t4 * 16;
            const float* pu2 = su2 + j * kPStr + t4 * 16;
            #pragma unroll
            for (int c4 = 0; c4 < 4; ++c4) {
                const float4 a = *(const float4*)(pu1 + c4 * 4);
                const float4 e = *(const float4*)(pu2 + c4 * 4);
                raw[c4*4+0] = a.x + e.x; raw[c4*4+1] = a.y + e.y;
                raw[c4*4+2] = a.z + e.z; raw[c4*4+3] = a.w + e.w;
                s1 += raw[c4*4+0] + raw[c4*4+1] + raw[c4*4+2] + raw[c4*4+3];
            }
        }
        s1 += __shfl_xor(s1, 1, 64); s1 += __shfl_xor(s1, 2, 64);
        const float mean = s1 * (1.f / 64.f);
        float s2 = 0.f;
        #pragma unroll
        for (int c = 0; c < 16; ++c) { const float d = raw[c] - mean; s2 = fmaf(d, d, s2); }
        s2 += __shfl_xor(s2, 1, 64); s2 += __shfl_xor(s2, 2, 64);
        const float rstd = rsqrtf(s2 * (1.f / 64.f) + 1e-5f);
        #pragma unroll
        for (int c = 0; c < 16; ++c) {
            const int k = t4 * 16 + c;
            vbT[k * kTStr + sl] = fmaxf(fmaf((raw[c] - mean) * rstd, slng[k], slnb[k]), 0.f);
        }
    }
    __syncthreads();

    // ---- phase B: V(64 slots x 64) @ sw2(64x32), 2 slots/lane ----
    {
        const int w = tid >> 6, l = tid & 63;
        const int sg8 = l >> 3, cq = l & 7;
        const int sl0 = w * 16 + sg8 * 2;             // slots sl0, sl0+1
        float4 a0 = {0,0,0,0}, a1 = {0,0,0,0};
        for (int k = 0; k < 64; ++k) {
            const float4 w4 = *(const float4*)&sw2s[k * 32 + cq * 4];
            const float2 v2 = *(const float2*)&vbT[k * kTStr + sl0];
            a0.x = fmaf(v2.x, w4.x, a0.x); a0.y = fmaf(v2.x, w4.y, a0.y);
            a0.z = fmaf(v2.x, w4.z, a0.z); a0.w = fmaf(v2.x, w4.w, a0.w);
            a1.x = fmaf(v2.y, w4.x, a1.x); a1.y = fmaf(v2.y, w4.y, a1.y);
            a1.z = fmaf(v2.y, w4.z, a1.z); a1.w = fmaf(v2.y, w4.w, a1.w);
        }
        const int o0 = cq * 4;
        float z0, z1;
        z0  = fmaxf(a0.x + ssb2[o0+0], 0.f) * ssw3[o0+0];
        z0 += fmaxf(a0.y + ssb2[o0+1], 0.f) * ssw3[o0+1];
        z0 += fmaxf(a0.z + ssb2[o0+2], 0.f) * ssw3[o0+2];
        z0 += fmaxf(a0.w + ssb2[o0+3], 0.f) * ssw3[o0+3];
        z1  = fmaxf(a1.x + ssb2[o0+0], 0.f) * ssw3[o0+0];
        z1 += fmaxf(a1.y + ssb2[o0+1], 0.f) * ssw3[o0+1];
        z1 += fmaxf(a1.z + ssb2[o0+2], 0.f) * ssw3[o0+2];
        z1 += fmaxf(a1.w + ssb2[o0+3], 0.f) * ssw3[o0+3];
        z0 += __shfl_xor(z0, 1, 64); z0 += __shfl_xor(z0, 2, 64); z0 += __shfl_xor(z0, 4, 64);
        z1 += __shfl_xor(z1, 1, 64); z1 += __shfl_xor(z1, 2, 64); z1 += __shfl_xor(z1, 4, 64);

        if (cq == 0) {
            const float alpha = 1.f / (1.f + __expf(-alpha_p[0]));
            const float cb2s  = cb2[0];
            #pragma unroll
            for (int e = 0; e < 2; ++e) {
                const int sl = sl0 + e;
                const float z = e ? z1 : z0;
                const int s_ = pb * 64 + sl;
                if (s_ < 253) {
                    int i, j; map_slot(s_, i, j);
                    const float zc1 = szc[sl * 2];
                    const float zc2 = szc[sl * 2 + 1];
                    const float wc1 = 1.f / (1.f + __expf(-(zc1 + cb2s)));
                    float gsem;
                    if (i == j) {
                        gsem = 1.f;
                    } else {
                        // accurate expf: this sigmoid feeds a hard threshold compare
                        const float wsem = 1.f / (1.f + expf(-(z + sb3[0])));
                        const float tt   = 1.f / (1.f + expf(-thr[0]));
                        gsem = (wsem > tt) ? wsem : 0.f;
                    }
                    const float gc1 = fmaf(sg[i * 22 + j], wc1, (i == j) ? 1.f : 0.f);
                    out[(size_t)b * kNP + i * 22 + j] = fmaf(alpha, gc1, (1.f - alpha) * gsem);
                    if (i != j) {
                        const float wc2 = 1.f / (1.f + __expf(-(zc2 + cb2s)));
                        const float gc2 = sg[j * 22 + i] * wc2;
                        out[(size_t)b * kNP + j * 22 + i] = fmaf(alpha, gc2, (1.f - alpha) * gsem);
                    }
                }
            }
        }
    }
}

extern "C" void kernel_launch(void* const* d_in, const int* in_sizes, int n_in,
                              void* d_out, int out_size, void* d_ws, size_t ws_size,
                              hipStream_t stream)
{
    (void)n_in; (void)out_size; (void)ws_size;
    const float* x     = (const float*)d_in[0];
    const float* cw1   = (const float*)d_in[1];
    const float* cb1   = (const float*)d_in[2];
    const float* cw2   = (const float*)d_in[3];
    const float* cb2   = (const float*)d_in[4];
    const float* emb   = (const float*)d_in[5];
    const float* sw1   = (const float*)d_in[6];
    const float* sb1   = (const float*)d_in[7];
    const float* ln_g  = (const float*)d_in[8];
    const float* ln_b  = (const float*)d_in[9];
    const float* sw2   = (const float*)d_in[10];
    const float* sb2   = (const float*)d_in[11];
    const float* sw3   = (const float*)d_in[12];
    const float* sb3   = (const float*)d_in[13];
    const float* thr   = (const float*)d_in[14];
    const float* alpha = (const float*)d_in[15];
    float* out = (float*)d_out;
    float* ws  = (float*)d_ws;

    const int B = in_sizes[0] / (kN * kF);
    const int M = kN * B;
    const int Mtiles = (M + 31) / 32;
    const int nGemm = Mtiles * 4;

    float* C = ws;                           // M x 256
    float* g = ws + (size_t)M * 256;         // B x 484

    hipLaunchKernelGGL(hgc_k1, dim3(nGemm + 2 * B), dim3(256), 0, stream,
                       x, cw1, cb1, emb, sw1, sb1, C, g, M, Mtiles, nGemm);
    hipLaunchKernelGGL(hgc_k2, dim3(4 * B), dim3(256), 0, stream,
                       C, g, cw2, cb2, sw2, sb2, sw3, sb3, ln_g, ln_b, thr, alpha, out);
}